// Round 11
// baseline (83.115 us; speedup 1.0000x reference)
//
#include <hip/hip_runtime.h>
#include <hip/hip_bf16.h>

#define NHID 512
#define PROJ 64
#define NC 4096
#define NEV 8192
#define NG 64
#define NCMAX 128
#define NE_CAP 256
#define DSLICES 8
#define DW 64
#define WE_S_STRIDE 72            // bf16 elems (64 + 8 pad)
#define EV_STRIDE 264             // bf16 elems per evT row (256 + 8 pad)
#define PG_STRIDE 256             // bf16 elems per P_g row

// ---- k_attn LDS layout (bytes) ----
#define WES_BYTES  (NE_CAP * WE_S_STRIDE * 2)      // 36864
#define WCS_OFF    WES_BYTES
#define UNION_END  (WES_BYTES + 16 * WE_S_STRIDE * 2)   // 39168 (>= evT 33792)
#define IDS_OFF    UNION_END
#define CLID_OFF   (IDS_OFF + 1024)
#define PP_OFF     (CLID_OFF + 512)
#define SMEM_BYTES (PP_OFF + 3072)                 // 43.7 KB -> 2+ blocks/CU

typedef __attribute__((ext_vector_type(8))) short s16x8;
typedef __attribute__((ext_vector_type(8))) unsigned short u16x8;
typedef __attribute__((ext_vector_type(4))) float f32x4;

static __device__ __forceinline__ unsigned short f2b(float f) {
  union { __hip_bfloat16 h; unsigned short u; } v;
  v.h = __float2bfloat16(f);
  return v.u;
}

// ---------------- compact_pairs: stable compaction -> (orig_pos, node_id) ----------------
template <int NPT>
__device__ __forceinline__ void compact_pairs(
    const int* __restrict__ batch, const int* __restrict__ idx, int g,
    int* __restrict__ off_out, int* __restrict__ cnt_out, int2* __restrict__ pairs) {
  __shared__ int wtot[4], wless[4];
  int t = threadIdx.x, lane = t & 63, w = t >> 6;
  int vals[NPT], nid[NPT];
  int base_i = t * NPT;
  int eq = 0, less = 0;
#pragma unroll
  for (int j = 0; j < NPT; j++) {
    int node = idx[base_i + j];
    int v = batch[node];
    vals[j] = v;
    nid[j] = node;
    eq += (v == g) ? 1 : 0;
    less += (v < g) ? 1 : 0;
  }
  int s = eq;
#pragma unroll
  for (int off = 1; off < 64; off <<= 1) {
    int o = __shfl_up(s, off);
    if (lane >= off) s += o;
  }
  int ls = less;
#pragma unroll
  for (int off = 32; off; off >>= 1) ls += __shfl_xor(ls, off);
  if (lane == 63) wtot[w] = s;
  if (lane == 0) wless[w] = ls;
  __syncthreads();
  int wbase = 0;
#pragma unroll
  for (int k = 0; k < 4; k++)
    if (k < w) wbase += wtot[k];
  int base = wless[0] + wless[1] + wless[2] + wless[3];
  int pos = base + wbase + (s - eq);
#pragma unroll
  for (int j = 0; j < NPT; j++) {
    if (vals[j] == g) pairs[pos++] = make_int2(base_i + j, nid[j]);
  }
  if (t == 255) {
    cnt_out[g] = wbase + s;
    off_out[g] = base;
  }
}

// ---------------- k_front: Wc/We transposes (0..15) + claim comp (16..79) + evid comp (80..143) ----------------
__global__ __launch_bounds__(256) void k_front(
    const float* __restrict__ Wc, const float* __restrict__ We,
    unsigned short* __restrict__ WcT, unsigned short* __restrict__ WeT,
    const int* __restrict__ batch, const int* __restrict__ cidx,
    const int* __restrict__ eidx, int* __restrict__ c_off, int* __restrict__ c_cnt,
    int2* __restrict__ c_pair, int* __restrict__ e_off, int* __restrict__ e_cnt,
    int2* __restrict__ e_pair, int* __restrict__ ctr) {
  int b = blockIdx.x;
  if (b == 0 && threadIdx.x == 0) *ctr = 0;   // re-zero every launch (graph replay)
  if (b < 16) {
    __shared__ float ts[64][65];
    const float* src = (b < 8) ? Wc : We;
    unsigned short* dst = (b < 8) ? WcT : WeT;
    int k0 = (b & 7) * 64;
    int t = threadIdx.x;
    int c = t & 63, r0 = t >> 6;
#pragma unroll
    for (int p = 0; p < 16; p++) {
      int r = r0 * 16 + p;
      ts[r][c] = src[(size_t)(k0 + r) * 64 + c];
    }
    __syncthreads();
    int n = t >> 2, q = t & 3;
    unsigned short tmp[16];
#pragma unroll
    for (int j = 0; j < 16; j++) tmp[j] = f2b(ts[q * 16 + j][n]);
    u16x8* dp = (u16x8*)(dst + (size_t)n * NHID + k0 + q * 16);
    dp[0] = *(u16x8*)tmp;
    dp[1] = *(u16x8*)(tmp + 8);
  } else if (b < 80) {
    compact_pairs<NC / 256>(batch, cidx, b - 16, c_off, c_cnt, c_pair);
  } else {
    compact_pairs<NEV / 256>(batch, eidx, b - 80, e_off, e_cnt, e_pair);
  }
}

// ---------------- k_proj: 768 GEMM blocks (16 rows, 4-way K-split) + 256 Wa-transpose blocks ----------------
__global__ __launch_bounds__(256) void k_proj(
    const float* __restrict__ x, const int* __restrict__ cidx,
    const int* __restrict__ eidx, const unsigned short* __restrict__ WcT,
    const unsigned short* __restrict__ WeT, const float* __restrict__ bc,
    const float* __restrict__ be, const float* __restrict__ Wa,
    unsigned short* __restrict__ WaT, unsigned short* __restrict__ wcp,
    unsigned short* __restrict__ wep) {
  __shared__ __align__(16) char sm[64 * 65 * 4];
  int b = blockIdx.x;
  int t = threadIdx.x;
  if (b >= 768) {
    int tb = b - 768;
    float(*ts)[65] = (float(*)[65])sm;
    int k0 = (tb >> 3) * 64, n0 = (tb & 7) * 64;
    int c = t & 63, r0 = t >> 6;
#pragma unroll
    for (int p = 0; p < 16; p++) {
      int r = r0 * 16 + p;
      ts[r][c] = Wa[(size_t)(k0 + r) * NHID + n0 + c];
    }
    __syncthreads();
    int n = t >> 2, q = t & 3;
    unsigned short tmp[16];
#pragma unroll
    for (int j = 0; j < 16; j++) tmp[j] = f2b(ts[q * 16 + j][n]);
    u16x8* dp = (u16x8*)(WaT + (size_t)(n0 + n) * (4 * NHID) + k0 + q * 16);
    dp[0] = *(u16x8*)tmp;
    dp[1] = *(u16x8*)(tmp + 8);
    return;
  }
  float(*red)[16][64] = (float(*)[16][64])sm;   // [4][16][64] = 16KB
  const int* idx; const unsigned short* WT; const float* bias;
  unsigned short* out; int base;
  if (b < NC / 16) { idx = cidx; WT = WcT; bias = bc; out = wcp; base = b * 16; }
  else             { idx = eidx; WT = WeT; bias = be; out = wep; base = (b - NC / 16) * 16; }
  int lane = t & 63, kh = t >> 6;     // kh = 4-way K-split
  int ln = lane & 15, kb = lane >> 4;
  const float* xr = x + (size_t)idx[base + ln] * NHID + kh * 128;
  const unsigned short* wb = WT + kh * 128;
  f32x4 acc[4];
#pragma unroll
  for (int nt = 0; nt < 4; nt++) acc[nt] = (f32x4){0.f, 0.f, 0.f, 0.f};
#pragma unroll
  for (int kt = 0; kt < 4; kt++) {
    int k0 = kt * 32 + kb * 8;
    float4 p0 = *(const float4*)(xr + k0);
    float4 p1 = *(const float4*)(xr + k0 + 4);
    s16x8 a;
    a[0] = (short)f2b(p0.x); a[1] = (short)f2b(p0.y);
    a[2] = (short)f2b(p0.z); a[3] = (short)f2b(p0.w);
    a[4] = (short)f2b(p1.x); a[5] = (short)f2b(p1.y);
    a[6] = (short)f2b(p1.z); a[7] = (short)f2b(p1.w);
#pragma unroll
    for (int nt = 0; nt < 4; nt++) {
      s16x8 bf = *(const s16x8*)(wb + (size_t)(nt * 16 + ln) * NHID + k0);
      acc[nt] = __builtin_amdgcn_mfma_f32_16x16x32_bf16(a, bf, acc[nt], 0, 0, 0);
    }
  }
#pragma unroll
  for (int nt = 0; nt < 4; nt++)
#pragma unroll
    for (int r = 0; r < 4; r++)
      red[kh][kb * 4 + r][nt * 16 + ln] = acc[nt][r];
  __syncthreads();
  for (int i = t; i < 512; i += 256) {
    int row = i >> 5, cp = i & 31;
    int c0 = cp * 2;
    float v0 = red[0][row][c0] + red[1][row][c0] + red[2][row][c0] + red[3][row][c0] + bias[c0];
    float v1 = red[0][row][c0 + 1] + red[1][row][c0 + 1] + red[2][row][c0 + 1] + red[3][row][c0 + 1] + bias[c0 + 1];
    unsigned int pk = (unsigned)f2b(v0) | ((unsigned)f2b(v1) << 16);
    *(unsigned int*)(out + (size_t)(base + row) * PROJ + c0) = pk;
  }
}

// ---------------- k_attn: fused score->P_g + grid barrier + PV + pooled sums ----------------
// 512 blocks = (g, ds in 0..7); 43.7KB LDS -> >=2 blocks/CU, all 512 co-resident.
__global__ __launch_bounds__(512, 4) void k_attn(
    const float* __restrict__ x, const unsigned short* __restrict__ wcp,
    const unsigned short* __restrict__ wep, const int* __restrict__ c_off,
    const int* __restrict__ c_cnt, const int2* __restrict__ c_pair,
    const int* __restrict__ e_off, const int* __restrict__ e_cnt,
    const int2* __restrict__ e_pair, unsigned short* __restrict__ P_g,
    unsigned short* __restrict__ mcb, int* __restrict__ ctr) {
  __shared__ __align__(16) char smem[SMEM_BYTES];
  unsigned short* we_s = (unsigned short*)(smem);
  unsigned short* wc_s = (unsigned short*)(smem + WCS_OFF);
  unsigned short* evT  = (unsigned short*)(smem);           // union with we_s/wc_s
  unsigned int*   evT32 = (unsigned int*)(smem);
  int* ev_id = (int*)(smem + IDS_OFF);
  int* cl_id = (int*)(smem + CLID_OFF);
  float* pp  = (float*)(smem + PP_OFF);                     // [4][3][64]

  int g = blockIdx.x >> 3;
  int ds = blockIdx.x & 7;
  int dsbase = ds * DW;
  int t = threadIdx.x, lane = t & 63, w = t >> 6;
  int ln = lane & 15, kb = lane >> 4;

  int ne = min(e_cnt[g], NE_CAP);
  int eoff = e_off[g];
  int ccnt_full = c_cnt[g];
  int nloc = min(ccnt_full, NCMAX);
  int coff = c_off[g];

  if (nloc <= 0) {
    if (t < 256) {
      int q = t >> 6, d = t & 63;
      mcb[(size_t)g * 4 * NHID + q * NHID + dsbase + d] = 0;
    }
    __syncthreads();
    if (t == 0) { __threadfence(); atomicAdd(ctr, 1); }
    return;
  }
  int KT = (ne + 31) >> 5;
  int NT = KT * 2;

  // ---- phase A: stage ids + we_s (full evidence) + wc_s (own 16-claim slice) ----
  for (int e = t; e < NE_CAP; e += 512)
    ev_id[e] = (e < ne) ? e_pair[eoff + e].y : 0;
  if (t < NCMAX) cl_id[t] = (t < nloc) ? c_pair[coff + t].y : 0;
  {
    int q = t & 7, er = t >> 3;
    for (int base_ = 0; base_ < NE_CAP; base_ += 64) {
      int e = base_ + er;
      u16x8 v = (u16x8){0, 0, 0, 0, 0, 0, 0, 0};
      if (e < ne) v = *(const u16x8*)(wep + (size_t)e_pair[eoff + e].x * PROJ + q * 8);
      *(u16x8*)(we_s + e * WE_S_STRIDE + q * 8) = v;
    }
    if (t < 128) {
      int cr = t >> 3;                 // 0..15 local claim
      int gc = ds * 16 + cr;
      u16x8 v = (u16x8){0, 0, 0, 0, 0, 0, 0, 0};
      if (gc < nloc) v = *(const u16x8*)(wcp + (size_t)c_pair[coff + gc].x * PROJ + q * 8);
      *(u16x8*)(wc_s + cr * WE_S_STRIDE + q * 8) = v;
    }
  }
  __syncthreads();

  // ---- phase B: score for this block's 16 claims (wave 0 only) -> P_g ----
  if (w == 0) {
    f32x4 sa[16];
#pragma unroll
    for (int i = 0; i < 16; i++) sa[i] = (f32x4){0.f, 0.f, 0.f, 0.f};
    const unsigned short* arow = wc_s + ln * WE_S_STRIDE;
#pragma unroll
    for (int ks = 0; ks < 2; ks++) {
      s16x8 af = *(const s16x8*)(arow + ks * 32 + kb * 8);
#pragma unroll
      for (int nt = 0; nt < 16; nt++) {
        if (nt < NT) {
          s16x8 bf = *(const s16x8*)(we_s + (nt * 16 + ln) * WE_S_STRIDE + ks * 32 + kb * 8);
          sa[nt] = __builtin_amdgcn_mfma_f32_16x16x32_bf16(af, bf, sa[nt], 0, 0, 0);
        }
      }
    }
#pragma unroll
    for (int r = 0; r < 4; r++) {
      int claim = (kb << 2) + r;       // 0..15 local
      float mx = -1e30f;
#pragma unroll
      for (int nt = 0; nt < 16; nt++) {
        if (nt < NT) {
          float v = sa[nt][r];
          v = (nt * 16 + ln < ne) ? v : -1e30f;
          sa[nt][r] = v;
          mx = fmaxf(mx, v);
        }
      }
      mx = fmaxf(mx, __shfl_xor(mx, 1));
      mx = fmaxf(mx, __shfl_xor(mx, 2));
      mx = fmaxf(mx, __shfl_xor(mx, 4));
      mx = fmaxf(mx, __shfl_xor(mx, 8));
      float sum = 0.f;
#pragma unroll
      for (int nt = 0; nt < 16; nt++) {
        if (nt < NT) {
          float p = __expf(sa[nt][r] - mx);
          sa[nt][r] = p;
          sum += p;
        }
      }
      sum += __shfl_xor(sum, 1);
      sum += __shfl_xor(sum, 2);
      sum += __shfl_xor(sum, 4);
      sum += __shfl_xor(sum, 8);
      float inv = 1.f / sum;
      int gclaim = ds * 16 + claim;
      if (gclaim < nloc) {
        unsigned short* prow = P_g + (size_t)(coff + gclaim) * PG_STRIDE;
#pragma unroll
        for (int nt = 0; nt < 16; nt++) {
          if (nt < NT) prow[nt * 16 + ln] = f2b(sa[nt][r] * inv);
        }
      }
    }
  }
  __syncthreads();                     // wave0 done with we_s/wc_s; P_g stores issued
  if (t == 0) { __threadfence(); atomicAdd(ctr, 1); }

  // ---- phase C: stage evT[d][e] (overlaps other blocks' score tails) ----
#pragma unroll
  for (int it = 0; it < 4; it++) {
    int idx2 = it * 512 + t;
    int ep = idx2 & 127;
    int dq = idx2 >> 7;                // 0..15
    int d0 = dq * 4;
    int e0 = ep * 2;
    float4 va = make_float4(0.f, 0.f, 0.f, 0.f);
    float4 vb = make_float4(0.f, 0.f, 0.f, 0.f);
    if (e0 < ne)     va = *(const float4*)(x + (size_t)ev_id[e0] * NHID + dsbase + d0);
    if (e0 + 1 < ne) vb = *(const float4*)(x + (size_t)ev_id[e0 + 1] * NHID + dsbase + d0);
    evT32[(d0 + 0) * (EV_STRIDE / 2) + ep] = (unsigned)f2b(va.x) | ((unsigned)f2b(vb.x) << 16);
    evT32[(d0 + 1) * (EV_STRIDE / 2) + ep] = (unsigned)f2b(va.y) | ((unsigned)f2b(vb.y) << 16);
    evT32[(d0 + 2) * (EV_STRIDE / 2) + ep] = (unsigned)f2b(va.z) | ((unsigned)f2b(vb.z) << 16);
    evT32[(d0 + 3) * (EV_STRIDE / 2) + ep] = (unsigned)f2b(va.w) | ((unsigned)f2b(vb.w) << 16);
  }

  // ---- grid barrier: wait for all 512 blocks' P_g ----
  if (t == 0) {
    while (__hip_atomic_load(ctr, __ATOMIC_ACQUIRE, __HIP_MEMORY_SCOPE_AGENT) < NG * DSLICES)
      __builtin_amdgcn_s_sleep(2);
  }
  __syncthreads();                     // evT writes + barrier both complete

  // ---- phase D: PV, A-fragments from global P_g ----
  int mw = w >> 1, nw = w & 1;
  int m0 = mw * 32, n0 = nw * 32;
  f32x4 pc[4];
#pragma unroll
  for (int i = 0; i < 4; i++) pc[i] = (f32x4){0.f, 0.f, 0.f, 0.f};
  {
    const unsigned short* prow0 = P_g + (size_t)(coff + m0 + ln) * PG_STRIDE + kb * 8;
    const unsigned short* prow1 = prow0 + 16 * PG_STRIDE;
#pragma unroll
    for (int kt = 0; kt < 8; kt++) {
      if (kt < KT) {
        int k0 = kt * 32;
        s16x8 a0 = *(const s16x8*)(prow0 + k0);
        s16x8 a1 = *(const s16x8*)(prow1 + k0);
#pragma unroll
        for (int nt = 0; nt < 2; nt++) {
          s16x8 bf = *(const s16x8*)(evT + (n0 + nt * 16 + ln) * EV_STRIDE + k0 + kb * 8);
          pc[nt]     = __builtin_amdgcn_mfma_f32_16x16x32_bf16(a0, bf, pc[nt], 0, 0, 0);
          pc[2 + nt] = __builtin_amdgcn_mfma_f32_16x16x32_bf16(a1, bf, pc[2 + nt], 0, 0, 0);
        }
      }
    }
  }

  // ---- phase E: fragment-direct pooled sums ----
#pragma unroll
  for (int nt = 0; nt < 2; nt++) {
    int d = n0 + nt * 16 + ln;
    float s_cl = 0.f, s_cn = 0.f, s_pr = 0.f;
#pragma unroll
    for (int mi = 0; mi < 2; mi++) {
      f32x4 v = pc[mi * 2 + nt];
#pragma unroll
      for (int r = 0; r < 4; r++) {
        int m = m0 + mi * 16 + kb * 4 + r;
        if (m < nloc) {
          float cn = v[r];
          float cl = x[(size_t)cl_id[m] * NHID + dsbase + d];
          s_cl += cl; s_cn += cn; s_pr += cl * cn;
        }
      }
    }
    s_cl += __shfl_xor(s_cl, 16); s_cl += __shfl_xor(s_cl, 32);
    s_cn += __shfl_xor(s_cn, 16); s_cn += __shfl_xor(s_cn, 32);
    s_pr += __shfl_xor(s_pr, 16); s_pr += __shfl_xor(s_pr, 32);
    if (kb == 0) {
      pp[(mw * 3 + 0) * DW + d] = s_cl;
      pp[(mw * 3 + 1) * DW + d] = s_cn;
      pp[(mw * 3 + 2) * DW + d] = s_pr;
    }
  }
  __syncthreads();

  // ---- mean-concat epilogue ----
  if (t < 256) {
    int q = t >> 6, d = t & 63;
    float inv = 1.f / (float)max(ccnt_full, 1);
    float v;
    if (q == 0) {
      v = pp[0 * DW + d] + pp[3 * DW + d] + pp[6 * DW + d] + pp[9 * DW + d];
    } else if (q == 1) {
      v = pp[1 * DW + d] + pp[4 * DW + d] + pp[7 * DW + d] + pp[10 * DW + d];
    } else if (q == 2) {
      float cl = pp[0 * DW + d] + pp[3 * DW + d] + pp[6 * DW + d] + pp[9 * DW + d];
      float cn = pp[1 * DW + d] + pp[4 * DW + d] + pp[7 * DW + d] + pp[10 * DW + d];
      v = cl - cn;
    } else {
      v = pp[2 * DW + d] + pp[5 * DW + d] + pp[8 * DW + d] + pp[11 * DW + d];
    }
    mcb[(size_t)g * 4 * NHID + q * NHID + dsbase + d] = f2b(v * inv);
  }
}

// ---------------- k_out: 32 blocks, 16-col n-tiles, 2-way K-split ----------------
__global__ __launch_bounds__(512) void k_out(
    const unsigned short* __restrict__ mc, const unsigned short* __restrict__ WaT,
    const float* __restrict__ ba, float* __restrict__ out) {
  __shared__ float red[2][64][16];   // 8KB
  int n0 = blockIdx.x * 16;
  int t = threadIdx.x, lane = t & 63, wv = t >> 6;
  int mh = wv & 3, kh = wv >> 2;
  int ln = lane & 15, kb = lane >> 4;
  f32x4 acc = (f32x4){0.f, 0.f, 0.f, 0.f};
  const unsigned short* arow = mc + (size_t)(mh * 16 + ln) * (4 * NHID) + kh * 1024;
  const unsigned short* wcol = WaT + (size_t)(n0 + ln) * (4 * NHID) + kh * 1024;
#pragma unroll 4
  for (int kt = 0; kt < 32; kt++) {
    int k0 = kt * 32 + kb * 8;
    s16x8 af = *(const s16x8*)(arow + k0);
    s16x8 bf = *(const s16x8*)(wcol + k0);
    acc = __builtin_amdgcn_mfma_f32_16x16x32_bf16(af, bf, acc, 0, 0, 0);
  }
#pragma unroll
  for (int r = 0; r < 4; r++)
    red[kh][mh * 16 + kb * 4 + r][ln] = acc[r];
  __syncthreads();
  for (int i = t; i < 1024; i += 512) {
    int row = i >> 4, col = i & 15;
    out[(size_t)row * NHID + n0 + col] = red[0][row][col] + red[1][row][col] + ba[n0 + col];
  }
}

extern "C" void kernel_launch(void* const* d_in, const int* in_sizes, int n_in,
                              void* d_out, int out_size, void* d_ws, size_t ws_size,
                              hipStream_t stream) {
  const float* x = (const float*)d_in[0];
  const int* batch = (const int*)d_in[1];
  const int* cidx = (const int*)d_in[2];
  const int* eidx = (const int*)d_in[3];
  const float* Wc = (const float*)d_in[4];
  const float* bc = (const float*)d_in[5];
  const float* We = (const float*)d_in[6];
  const float* be = (const float*)d_in[7];
  const float* Wa = (const float*)d_in[8];
  const float* ba = (const float*)d_in[9];
  float* out = (float*)d_out;

  char* w = (char*)d_ws;
  int* c_off = (int*)w;    w += NG * 4;
  int* c_cnt = (int*)w;    w += NG * 4;
  int* e_off = (int*)w;    w += NG * 4;
  int* e_cnt = (int*)w;    w += NG * 4;
  int* ctr = (int*)w;      w += 64;           // 64B-aligned counter slot
  int2* c_pair = (int2*)w; w += (size_t)NC * 8;
  int2* e_pair = (int2*)w; w += (size_t)NEV * 8;
  unsigned short* wcp = (unsigned short*)w; w += (size_t)NC * PROJ * 2;
  unsigned short* wep = (unsigned short*)w; w += (size_t)NEV * PROJ * 2;
  unsigned short* WcT = (unsigned short*)w; w += (size_t)PROJ * NHID * 2;
  unsigned short* WeT = (unsigned short*)w; w += (size_t)PROJ * NHID * 2;
  unsigned short* WaT = (unsigned short*)w; w += (size_t)NHID * 4 * NHID * 2;
  unsigned short* mcb = (unsigned short*)w; w += (size_t)NG * 4 * NHID * 2;
  unsigned short* P_g = (unsigned short*)w; w += (size_t)(NC + NCMAX) * PG_STRIDE * 2;

  k_front<<<144, 256, 0, stream>>>(Wc, We, WcT, WeT, batch, cidx, eidx,
                                   c_off, c_cnt, c_pair, e_off, e_cnt, e_pair, ctr);
  k_proj<<<768 + 256, 256, 0, stream>>>(x, cidx, eidx, WcT, WeT, bc, be, Wa, WaT,
                                        wcp, wep);
  k_attn<<<NG * DSLICES, 512, 0, stream>>>(x, wcp, wep, c_off, c_cnt, c_pair,
                                           e_off, e_cnt, e_pair, P_g, mcb, ctr);
  k_out<<<32, 512, 0, stream>>>(mcb, WaT, ba, out);
}

// Round 12
// 61.906 us; speedup vs baseline: 1.3426x; 1.3426x over previous
//
#include <hip/hip_runtime.h>
#include <hip/hip_bf16.h>

#define NHID 512
#define PROJ 64
#define NC 4096
#define NEV 8192
#define NG 64
#define NCMAX 128
#define NE_CAP 256
#define DSLICES 4
#define DW 128

typedef __attribute__((ext_vector_type(8))) short s16x8;
typedef __attribute__((ext_vector_type(8))) unsigned short u16x8;
typedef __attribute__((ext_vector_type(4))) float f32x4;

// ---- k_attn LDS layout (bytes) ----
#define P_S_STRIDE 264            // bf16 elems per row (256 + 8 pad), 528B
#define P_S_BYTES  (NCMAX * P_S_STRIDE * 2)        // 67584
#define REGB_OFF   P_S_BYTES
#define WE_S_STRIDE 72            // bf16 elems (64 + 8 pad), 144B
#define WC_S_OFF   (REGB_OFF + NE_CAP * WE_S_STRIDE * 2)
#define CN_S_STRIDE 132           // f32 elems per row
#define MISC_OFF   (REGB_OFF + P_S_BYTES)
#define SMEM_BYTES (MISC_OFF + 1536)

static __device__ __forceinline__ unsigned short f2b(float f) {
  union { __hip_bfloat16 h; unsigned short u; } v;
  v.h = __float2bfloat16(f);
  return v.u;
}

// ---------------- compact_pairs: stable compaction -> (orig_pos, node_id) ----------------
template <int NPT>
__device__ __forceinline__ void compact_pairs(
    const int* __restrict__ batch, const int* __restrict__ idx, int g,
    int* __restrict__ off_out, int* __restrict__ cnt_out, int2* __restrict__ pairs) {
  __shared__ int wtot[4], wless[4];
  int t = threadIdx.x, lane = t & 63, w = t >> 6;
  int vals[NPT], nid[NPT];
  int base_i = t * NPT;
  int eq = 0, less = 0;
#pragma unroll
  for (int j = 0; j < NPT; j++) {
    int node = idx[base_i + j];
    int v = batch[node];
    vals[j] = v;
    nid[j] = node;
    eq += (v == g) ? 1 : 0;
    less += (v < g) ? 1 : 0;
  }
  int s = eq;
#pragma unroll
  for (int off = 1; off < 64; off <<= 1) {
    int o = __shfl_up(s, off);
    if (lane >= off) s += o;
  }
  int ls = less;
#pragma unroll
  for (int off = 32; off; off >>= 1) ls += __shfl_xor(ls, off);
  if (lane == 63) wtot[w] = s;
  if (lane == 0) wless[w] = ls;
  __syncthreads();
  int wbase = 0;
#pragma unroll
  for (int k = 0; k < 4; k++)
    if (k < w) wbase += wtot[k];
  int base = wless[0] + wless[1] + wless[2] + wless[3];
  int pos = base + wbase + (s - eq);
#pragma unroll
  for (int j = 0; j < NPT; j++) {
    if (vals[j] == g) pairs[pos++] = make_int2(base_i + j, nid[j]);
  }
  if (t == 255) {
    cnt_out[g] = wbase + s;
    off_out[g] = base;
  }
}

// ---------------- k_front: Wc/We transposes (0..15) + claim comp (16..79) + evid comp (80..143) ----------------
__global__ __launch_bounds__(256) void k_front(
    const float* __restrict__ Wc, const float* __restrict__ We,
    unsigned short* __restrict__ WcT, unsigned short* __restrict__ WeT,
    const int* __restrict__ batch, const int* __restrict__ cidx,
    const int* __restrict__ eidx, int* __restrict__ c_off, int* __restrict__ c_cnt,
    int2* __restrict__ c_pair, int* __restrict__ e_off, int* __restrict__ e_cnt,
    int2* __restrict__ e_pair) {
  int b = blockIdx.x;
  if (b < 16) {
    __shared__ float ts[64][65];
    const float* src = (b < 8) ? Wc : We;
    unsigned short* dst = (b < 8) ? WcT : WeT;
    int k0 = (b & 7) * 64;
    int t = threadIdx.x;
    int c = t & 63, r0 = t >> 6;
#pragma unroll
    for (int p = 0; p < 16; p++) {
      int r = r0 * 16 + p;
      ts[r][c] = src[(size_t)(k0 + r) * 64 + c];
    }
    __syncthreads();
    int n = t >> 2, q = t & 3;
    unsigned short tmp[16];
#pragma unroll
    for (int j = 0; j < 16; j++) tmp[j] = f2b(ts[q * 16 + j][n]);
    u16x8* dp = (u16x8*)(dst + (size_t)n * NHID + k0 + q * 16);
    dp[0] = *(u16x8*)tmp;
    dp[1] = *(u16x8*)(tmp + 8);
  } else if (b < 80) {
    compact_pairs<NC / 256>(batch, cidx, b - 16, c_off, c_cnt, c_pair);
  } else {
    compact_pairs<NEV / 256>(batch, eidx, b - 80, e_off, e_cnt, e_pair);
  }
}

// ---------------- k_proj: 768 GEMM blocks (16 rows, 4-way K-split) + 256 Wa-transpose blocks ----------------
__global__ __launch_bounds__(256) void k_proj(
    const float* __restrict__ x, const int* __restrict__ cidx,
    const int* __restrict__ eidx, const unsigned short* __restrict__ WcT,
    const unsigned short* __restrict__ WeT, const float* __restrict__ bc,
    const float* __restrict__ be, const float* __restrict__ Wa,
    unsigned short* __restrict__ WaT, unsigned short* __restrict__ wcp,
    unsigned short* __restrict__ wep) {
  __shared__ __align__(16) char sm[64 * 65 * 4];
  int b = blockIdx.x;
  int t = threadIdx.x;
  if (b >= 768) {
    int tb = b - 768;
    float(*ts)[65] = (float(*)[65])sm;
    int k0 = (tb >> 3) * 64, n0 = (tb & 7) * 64;
    int c = t & 63, r0 = t >> 6;
#pragma unroll
    for (int p = 0; p < 16; p++) {
      int r = r0 * 16 + p;
      ts[r][c] = Wa[(size_t)(k0 + r) * NHID + n0 + c];
    }
    __syncthreads();
    int n = t >> 2, q = t & 3;
    unsigned short tmp[16];
#pragma unroll
    for (int j = 0; j < 16; j++) tmp[j] = f2b(ts[q * 16 + j][n]);
    u16x8* dp = (u16x8*)(WaT + (size_t)(n0 + n) * (4 * NHID) + k0 + q * 16);
    dp[0] = *(u16x8*)tmp;
    dp[1] = *(u16x8*)(tmp + 8);
    return;
  }
  float(*red)[16][64] = (float(*)[16][64])sm;   // [4][16][64] = 16KB
  const int* idx; const unsigned short* WT; const float* bias;
  unsigned short* out; int base;
  if (b < NC / 16) { idx = cidx; WT = WcT; bias = bc; out = wcp; base = b * 16; }
  else             { idx = eidx; WT = WeT; bias = be; out = wep; base = (b - NC / 16) * 16; }
  int lane = t & 63, kh = t >> 6;     // kh = 4-way K-split
  int ln = lane & 15, kb = lane >> 4;
  const float* xr = x + (size_t)idx[base + ln] * NHID + kh * 128;
  const unsigned short* wb = WT + kh * 128;
  f32x4 acc[4];
#pragma unroll
  for (int nt = 0; nt < 4; nt++) acc[nt] = (f32x4){0.f, 0.f, 0.f, 0.f};
#pragma unroll
  for (int kt = 0; kt < 4; kt++) {
    int k0 = kt * 32 + kb * 8;
    float4 p0 = *(const float4*)(xr + k0);
    float4 p1 = *(const float4*)(xr + k0 + 4);
    s16x8 a;
    a[0] = (short)f2b(p0.x); a[1] = (short)f2b(p0.y);
    a[2] = (short)f2b(p0.z); a[3] = (short)f2b(p0.w);
    a[4] = (short)f2b(p1.x); a[5] = (short)f2b(p1.y);
    a[6] = (short)f2b(p1.z); a[7] = (short)f2b(p1.w);
#pragma unroll
    for (int nt = 0; nt < 4; nt++) {
      s16x8 bf = *(const s16x8*)(wb + (size_t)(nt * 16 + ln) * NHID + k0);
      acc[nt] = __builtin_amdgcn_mfma_f32_16x16x32_bf16(a, bf, acc[nt], 0, 0, 0);
    }
  }
#pragma unroll
  for (int nt = 0; nt < 4; nt++)
#pragma unroll
    for (int r = 0; r < 4; r++)
      red[kh][kb * 4 + r][nt * 16 + ln] = acc[nt][r];
  __syncthreads();
  for (int i = t; i < 512; i += 256) {
    int row = i >> 5, cp = i & 31;
    int c0 = cp * 2;
    float v0 = red[0][row][c0] + red[1][row][c0] + red[2][row][c0] + red[3][row][c0] + bias[c0];
    float v1 = red[0][row][c0 + 1] + red[1][row][c0 + 1] + red[2][row][c0 + 1] + red[3][row][c0 + 1] + bias[c0 + 1];
    unsigned int pk = (unsigned)f2b(v0) | ((unsigned)f2b(v1) << 16);
    *(unsigned int*)(out + (size_t)(base + row) * PROJ + c0) = pk;
  }
}

// ---------------- k_attn: MFMA attention, coalesced wave-per-row evT gather ----------------
__global__ __launch_bounds__(512, 2) void k_attn(
    const float* __restrict__ x, const unsigned short* __restrict__ wcp,
    const unsigned short* __restrict__ wep, const int* __restrict__ c_off,
    const int* __restrict__ c_cnt, const int2* __restrict__ c_pair,
    const int* __restrict__ e_off, const int* __restrict__ e_cnt,
    const int2* __restrict__ e_pair, unsigned short* __restrict__ mcb) {
  __shared__ __align__(16) char smem[SMEM_BYTES];
  unsigned short* P_s  = (unsigned short*)(smem);
  unsigned short* we_s = (unsigned short*)(smem + REGB_OFF);
  unsigned short* wc_s = (unsigned short*)(smem + WC_S_OFF);
  unsigned short* evT  = (unsigned short*)(smem + REGB_OFF);
  unsigned int*   evT32 = (unsigned int*)(smem + REGB_OFF);
  float*          cn_s = (float*)(smem + REGB_OFF);
  float*          pp   = (float*)(smem);          // reuses dead P_s region post-PV
  int* ev_id = (int*)(smem + MISC_OFF);
  int* cl_id = (int*)(smem + MISC_OFF + 1024);

  int g = blockIdx.x >> 2;
  int ds = blockIdx.x & 3;
  int dsbase = ds * DW;
  int t = threadIdx.x, lane = t & 63, w = t >> 6;
  int ln = lane & 15, kb = lane >> 4;

  int ne = min(e_cnt[g], NE_CAP);
  int eoff = e_off[g];
  int ccnt_full = c_cnt[g];
  int nloc = min(ccnt_full, NCMAX);
  int coff = c_off[g];
  if (nloc <= 0) {
    int q = t >> 7, d = t & 127;
    mcb[(size_t)g * 4 * NHID + q * NHID + dsbase + d] = 0;
    return;
  }
  int KT = (ne + 31) >> 5;
  int NT = KT * 2;

  // ---- phase 0: stage ids + we_s + wc_s (1-level gathers via pairs) ----
  for (int e = t; e < NE_CAP; e += 512)
    ev_id[e] = (e < ne) ? e_pair[eoff + e].y : 0;
  if (t < NCMAX) cl_id[t] = (t < nloc) ? c_pair[coff + t].y : 0;
  {
    int q = t & 7, er = t >> 3;
    for (int base_ = 0; base_ < NE_CAP; base_ += 64) {
      int e = base_ + er;
      u16x8 v = (u16x8){0, 0, 0, 0, 0, 0, 0, 0};
      if (e < ne) v = *(const u16x8*)(wep + (size_t)e_pair[eoff + e].x * PROJ + q * 8);
      *(u16x8*)(we_s + e * WE_S_STRIDE + q * 8) = v;
    }
    for (int base_ = 0; base_ < NCMAX; base_ += 64) {
      int c = base_ + er;
      u16x8 v = (u16x8){0, 0, 0, 0, 0, 0, 0, 0};
      if (c < nloc) v = *(const u16x8*)(wcp + (size_t)c_pair[coff + c].x * PROJ + q * 8);
      *(u16x8*)(wc_s + c * WE_S_STRIDE + q * 8) = v;
    }
  }
  __syncthreads();

  // ---- score phase: S = wc @ we^T via MFMA ----
  {
    f32x4 sa[16];
#pragma unroll
    for (int i = 0; i < 16; i++) sa[i] = (f32x4){0.f, 0.f, 0.f, 0.f};
    const unsigned short* arow = wc_s + ((w << 4) + ln) * WE_S_STRIDE;
#pragma unroll
    for (int ks = 0; ks < 2; ks++) {
      s16x8 af = *(const s16x8*)(arow + ks * 32 + kb * 8);
#pragma unroll
      for (int nt = 0; nt < 16; nt++) {
        if (nt < NT) {
          s16x8 bf = *(const s16x8*)(we_s + (nt * 16 + ln) * WE_S_STRIDE + ks * 32 + kb * 8);
          sa[nt] = __builtin_amdgcn_mfma_f32_16x16x32_bf16(af, bf, sa[nt], 0, 0, 0);
        }
      }
    }
#pragma unroll
    for (int r = 0; r < 4; r++) {
      int claim = (w << 4) + (kb << 2) + r;
      float mx = -1e30f;
#pragma unroll
      for (int nt = 0; nt < 16; nt++) {
        if (nt < NT) {
          float v = sa[nt][r];
          v = (nt * 16 + ln < ne) ? v : -1e30f;
          sa[nt][r] = v;
          mx = fmaxf(mx, v);
        }
      }
      mx = fmaxf(mx, __shfl_xor(mx, 1));
      mx = fmaxf(mx, __shfl_xor(mx, 2));
      mx = fmaxf(mx, __shfl_xor(mx, 4));
      mx = fmaxf(mx, __shfl_xor(mx, 8));
      float sum = 0.f;
#pragma unroll
      for (int nt = 0; nt < 16; nt++) {
        if (nt < NT) {
          float p = __expf(sa[nt][r] - mx);
          sa[nt][r] = p;
          sum += p;
        }
      }
      sum += __shfl_xor(sum, 1);
      sum += __shfl_xor(sum, 2);
      sum += __shfl_xor(sum, 4);
      sum += __shfl_xor(sum, 8);
      float inv = 1.f / sum;
#pragma unroll
      for (int nt = 0; nt < 16; nt++) {
        if (nt < NT)
          P_s[claim * P_S_STRIDE + nt * 16 + ln] = f2b(sa[nt][r] * inv);
      }
    }
  }
  __syncthreads();   // we_s dead; P_s ready

  // ---- evT staging: COALESCED wave-per-row-pair; lane l reads float2 (d=2l,2l+1) ----
  // One wave instruction = 512B contiguous (vs 64 scattered 16B lines before).
#pragma unroll 4
  for (int pi = w; pi < NE_CAP / 2; pi += 8) {
    int e0 = pi * 2;
    float2 va = make_float2(0.f, 0.f);
    float2 vb = make_float2(0.f, 0.f);
    if (e0 < ne)     va = *(const float2*)(x + (size_t)ev_id[e0] * NHID + dsbase + 2 * lane);
    if (e0 + 1 < ne) vb = *(const float2*)(x + (size_t)ev_id[e0 + 1] * NHID + dsbase + 2 * lane);
    evT32[(2 * lane)     * (P_S_STRIDE / 2) + pi] = (unsigned)f2b(va.x) | ((unsigned)f2b(vb.x) << 16);
    evT32[(2 * lane + 1) * (P_S_STRIDE / 2) + pi] = (unsigned)f2b(va.y) | ((unsigned)f2b(vb.y) << 16);
  }
  __syncthreads();

  // ---- T14: issue claim-row loads for pooled phase; PV hides latency ----
  int dq4 = (t & 31) * 4;
  int mg = t >> 5;     // 0..15
  float4 cl_r[8];
#pragma unroll
  for (int mi = 0; mi < 8; mi++) {
    int m = mg + mi * 16;
    cl_r[mi] = make_float4(0.f, 0.f, 0.f, 0.f);
    if (m < nloc)
      cl_r[mi] = *(const float4*)(x + (size_t)cl_id[m] * NHID + dsbase + dq4);
  }

  // ---- PV phase ----
  int mw = w >> 1, nw = w & 1;
  int m0 = mw * 32, n0 = nw * 64;
  f32x4 pc[8];
#pragma unroll
  for (int i = 0; i < 8; i++) pc[i] = (f32x4){0.f, 0.f, 0.f, 0.f};
  {
    const unsigned short* prow0 = P_s + (m0 + ln) * P_S_STRIDE + kb * 8;
    const unsigned short* prow1 = prow0 + 16 * P_S_STRIDE;
#pragma unroll
    for (int kt = 0; kt < 8; kt++) {
      if (kt < KT) {
        int k0 = kt * 32;
        s16x8 a0 = *(const s16x8*)(prow0 + k0);
        s16x8 a1 = *(const s16x8*)(prow1 + k0);
#pragma unroll
        for (int nt = 0; nt < 4; nt++) {
          s16x8 bf = *(const s16x8*)(evT + (n0 + nt * 16 + ln) * P_S_STRIDE + k0 + kb * 8);
          pc[nt]     = __builtin_amdgcn_mfma_f32_16x16x32_bf16(a0, bf, pc[nt], 0, 0, 0);
          pc[4 + nt] = __builtin_amdgcn_mfma_f32_16x16x32_bf16(a1, bf, pc[4 + nt], 0, 0, 0);
        }
      }
    }
  }
  __syncthreads();   // P_s dead from here; pp may reuse its region

  // ---- dump cn to LDS ----
#pragma unroll
  for (int mi = 0; mi < 2; mi++) {
#pragma unroll
    for (int nt = 0; nt < 4; nt++) {
      f32x4 v = pc[mi * 4 + nt];
#pragma unroll
      for (int r = 0; r < 4; r++)
        cn_s[(m0 + mi * 16 + (kb << 2) + r) * CN_S_STRIDE + n0 + nt * 16 + ln] = v[r];
    }
  }
  __syncthreads();

  // ---- pooled sums: staged claim regs + cn_s, partials into pp ----
  {
    float4 scl = make_float4(0.f, 0.f, 0.f, 0.f);
    float4 scn = make_float4(0.f, 0.f, 0.f, 0.f);
    float4 spr = make_float4(0.f, 0.f, 0.f, 0.f);
#pragma unroll
    for (int mi = 0; mi < 8; mi++) {
      int m = mg + mi * 16;
      if (m < nloc) {
        float4 cl = cl_r[mi];
        float4 cn = *(const float4*)(cn_s + m * CN_S_STRIDE + dq4);
        scl.x += cl.x; scl.y += cl.y; scl.z += cl.z; scl.w += cl.w;
        scn.x += cn.x; scn.y += cn.y; scn.z += cn.z; scn.w += cn.w;
        spr.x += cl.x * cn.x; spr.y += cl.y * cn.y;
        spr.z += cl.z * cn.z; spr.w += cl.w * cn.w;
      }
    }
    *(float4*)(pp + mg * 128 + dq4) = scl;
    *(float4*)(pp + 2048 + mg * 128 + dq4) = scn;
    *(float4*)(pp + 4096 + mg * 128 + dq4) = spr;
  }
  __syncthreads();

  // ---- fused mean-concat epilogue ----
  {
    int q = t >> 7, d = t & 127;
    float inv = 1.f / (float)max(ccnt_full, 1);
    float v = 0.f;
    if (q == 0) {
#pragma unroll
      for (int mg2 = 0; mg2 < 16; mg2++) v += pp[mg2 * 128 + d];
    } else if (q == 1) {
#pragma unroll
      for (int mg2 = 0; mg2 < 16; mg2++) v += pp[2048 + mg2 * 128 + d];
    } else if (q == 2) {
#pragma unroll
      for (int mg2 = 0; mg2 < 16; mg2++) v += pp[mg2 * 128 + d] - pp[2048 + mg2 * 128 + d];
    } else {
#pragma unroll
      for (int mg2 = 0; mg2 < 16; mg2++) v += pp[4096 + mg2 * 128 + d];
    }
    mcb[(size_t)g * 4 * NHID + q * NHID + dsbase + d] = f2b(v * inv);
  }
}

// ---------------- k_out: 32 blocks, 16-col n-tiles, 2-way K-split ----------------
__global__ __launch_bounds__(512) void k_out(
    const unsigned short* __restrict__ mc, const unsigned short* __restrict__ WaT,
    const float* __restrict__ ba, float* __restrict__ out) {
  __shared__ float red[2][64][16];   // 8KB
  int n0 = blockIdx.x * 16;
  int t = threadIdx.x, lane = t & 63, wv = t >> 6;
  int mh = wv & 3, kh = wv >> 2;
  int ln = lane & 15, kb = lane >> 4;
  f32x4 acc = (f32x4){0.f, 0.f, 0.f, 0.f};
  const unsigned short* arow = mc + (size_t)(mh * 16 + ln) * (4 * NHID) + kh * 1024;
  const unsigned short* wcol = WaT + (size_t)(n0 + ln) * (4 * NHID) + kh * 1024;
#pragma unroll 4
  for (int kt = 0; kt < 32; kt++) {
    int k0 = kt * 32 + kb * 8;
    s16x8 af = *(const s16x8*)(arow + k0);
    s16x8 bf = *(const s16x8*)(wcol + k0);
    acc = __builtin_amdgcn_mfma_f32_16x16x32_bf16(af, bf, acc, 0, 0, 0);
  }
#pragma unroll
  for (int r = 0; r < 4; r++)
    red[kh][mh * 16 + kb * 4 + r][ln] = acc[r];
  __syncthreads();
  for (int i = t; i < 1024; i += 512) {
    int row = i >> 4, col = i & 15;
    out[(size_t)row * NHID + n0 + col] = red[0][row][col] + red[1][row][col] + ba[n0 + col];
  }
}

extern "C" void kernel_launch(void* const* d_in, const int* in_sizes, int n_in,
                              void* d_out, int out_size, void* d_ws, size_t ws_size,
                              hipStream_t stream) {
  const float* x = (const float*)d_in[0];
  const int* batch = (const int*)d_in[1];
  const int* cidx = (const int*)d_in[2];
  const int* eidx = (const int*)d_in[3];
  const float* Wc = (const float*)d_in[4];
  const float* bc = (const float*)d_in[5];
  const float* We = (const float*)d_in[6];
  const float* be = (const float*)d_in[7];
  const float* Wa = (const float*)d_in[8];
  const float* ba = (const float*)d_in[9];
  float* out = (float*)d_out;

  char* w = (char*)d_ws;
  int* c_off = (int*)w;    w += NG * 4;
  int* c_cnt = (int*)w;    w += NG * 4;
  int* e_off = (int*)w;    w += NG * 4;
  int* e_cnt = (int*)w;    w += NG * 4;
  int2* c_pair = (int2*)w; w += (size_t)NC * 8;
  int2* e_pair = (int2*)w; w += (size_t)NEV * 8;
  unsigned short* wcp = (unsigned short*)w; w += (size_t)NC * PROJ * 2;
  unsigned short* wep = (unsigned short*)w; w += (size_t)NEV * PROJ * 2;
  unsigned short* WcT = (unsigned short*)w; w += (size_t)PROJ * NHID * 2;
  unsigned short* WeT = (unsigned short*)w; w += (size_t)PROJ * NHID * 2;
  unsigned short* WaT = (unsigned short*)w; w += (size_t)NHID * 4 * NHID * 2;
  unsigned short* mcb = (unsigned short*)w; w += (size_t)NG * 4 * NHID * 2;

  k_front<<<144, 256, 0, stream>>>(Wc, We, WcT, WeT, batch, cidx, eidx,
                                   c_off, c_cnt, c_pair, e_off, e_cnt, e_pair);
  k_proj<<<768 + 256, 256, 0, stream>>>(x, cidx, eidx, WcT, WeT, bc, be, Wa, WaT,
                                        wcp, wep);
  k_attn<<<NG * DSLICES, 512, 0, stream>>>(x, wcp, wep, c_off, c_cnt, c_pair,
                                           e_off, e_cnt, e_pair, mcb);
  k_out<<<32, 512, 0, stream>>>(mcb, WaT, ba, out);
}

// Round 13
// 56.621 us; speedup vs baseline: 1.4679x; 1.0933x over previous
//
#include <hip/hip_runtime.h>
#include <hip/hip_bf16.h>

#define NHID 512
#define PROJ 64
#define NC 4096
#define NEV 8192
#define NG 64
#define NCMAX 128
#define NE_CAP 256
#define DSLICES 4
#define DW 128

typedef __attribute__((ext_vector_type(8))) short s16x8;
typedef __attribute__((ext_vector_type(8))) unsigned short u16x8;
typedef __attribute__((ext_vector_type(4))) float f32x4;

// ---- k_attn LDS layout (bytes) ----
#define P_S_STRIDE 264            // bf16 elems per row (256 + 8 pad), 528B
#define P_S_BYTES  (NCMAX * P_S_STRIDE * 2)        // 67584
#define REGB_OFF   P_S_BYTES
#define WE_S_STRIDE 72            // bf16 elems (64 + 8 pad), 144B
#define WC_S_OFF   (REGB_OFF + NE_CAP * WE_S_STRIDE * 2)
#define CN_S_STRIDE 132           // f32 elems per row
#define SMEM_BYTES (REGB_OFF + P_S_BYTES)

static __device__ __forceinline__ unsigned short f2b(float f) {
  union { __hip_bfloat16 h; unsigned short u; } v;
  v.h = __float2bfloat16(f);
  return v.u;
}
static __device__ __forceinline__ float b2f(unsigned short u) {
  union { unsigned short u; __hip_bfloat16 h; } v;
  v.u = u;
  return __bfloat162float(v.h);
}

// ---------------- compact_pairs: stable compaction -> (orig_pos, node_id) ----------------
template <int NPT>
__device__ __forceinline__ void compact_pairs(
    const int* __restrict__ batch, const int* __restrict__ idx, int g,
    int* __restrict__ off_out, int* __restrict__ cnt_out, int2* __restrict__ pairs) {
  __shared__ int wtot[4], wless[4];
  int t = threadIdx.x, lane = t & 63, w = t >> 6;
  int vals[NPT], nid[NPT];
  int base_i = t * NPT;
  int eq = 0, less = 0;
#pragma unroll
  for (int j = 0; j < NPT; j++) {
    int node = idx[base_i + j];
    int v = batch[node];
    vals[j] = v;
    nid[j] = node;
    eq += (v == g) ? 1 : 0;
    less += (v < g) ? 1 : 0;
  }
  int s = eq;
#pragma unroll
  for (int off = 1; off < 64; off <<= 1) {
    int o = __shfl_up(s, off);
    if (lane >= off) s += o;
  }
  int ls = less;
#pragma unroll
  for (int off = 32; off; off >>= 1) ls += __shfl_xor(ls, off);
  if (lane == 63) wtot[w] = s;
  if (lane == 0) wless[w] = ls;
  __syncthreads();
  int wbase = 0;
#pragma unroll
  for (int k = 0; k < 4; k++)
    if (k < w) wbase += wtot[k];
  int base = wless[0] + wless[1] + wless[2] + wless[3];
  int pos = base + wbase + (s - eq);
#pragma unroll
  for (int j = 0; j < NPT; j++) {
    if (vals[j] == g) pairs[pos++] = make_int2(base_i + j, nid[j]);
  }
  if (t == 255) {
    cnt_out[g] = wbase + s;
    off_out[g] = base;
  }
}

// ---------------- k_front: Wc/We transposes (0..15) + claim comp (16..79) + evid comp (80..143) ----------------
__global__ __launch_bounds__(256) void k_front(
    const float* __restrict__ Wc, const float* __restrict__ We,
    unsigned short* __restrict__ WcT, unsigned short* __restrict__ WeT,
    const int* __restrict__ batch, const int* __restrict__ cidx,
    const int* __restrict__ eidx, int* __restrict__ c_off, int* __restrict__ c_cnt,
    int2* __restrict__ c_pair, int* __restrict__ e_off, int* __restrict__ e_cnt,
    int2* __restrict__ e_pair) {
  int b = blockIdx.x;
  if (b < 16) {
    __shared__ float ts[64][65];
    const float* src = (b < 8) ? Wc : We;
    unsigned short* dst = (b < 8) ? WcT : WeT;
    int k0 = (b & 7) * 64;
    int t = threadIdx.x;
    int c = t & 63, r0 = t >> 6;
#pragma unroll
    for (int p = 0; p < 16; p++) {
      int r = r0 * 16 + p;
      ts[r][c] = src[(size_t)(k0 + r) * 64 + c];
    }
    __syncthreads();
    int n = t >> 2, q = t & 3;
    unsigned short tmp[16];
#pragma unroll
    for (int j = 0; j < 16; j++) tmp[j] = f2b(ts[q * 16 + j][n]);
    u16x8* dp = (u16x8*)(dst + (size_t)n * NHID + k0 + q * 16);
    dp[0] = *(u16x8*)tmp;
    dp[1] = *(u16x8*)(tmp + 8);
  } else if (b < 80) {
    compact_pairs<NC / 256>(batch, cidx, b - 16, c_off, c_cnt, c_pair);
  } else {
    compact_pairs<NEV / 256>(batch, eidx, b - 80, e_off, e_cnt, e_pair);
  }
}

// ---------------- k_proj: compacted-order GEMM (768 blocks) + x bf16 row export + Wa transpose ----------------
__global__ __launch_bounds__(256) void k_proj(
    const float* __restrict__ x, const int2* __restrict__ c_pair,
    const int2* __restrict__ e_pair, const unsigned short* __restrict__ WcT,
    const unsigned short* __restrict__ WeT, const float* __restrict__ bc,
    const float* __restrict__ be, const float* __restrict__ Wa,
    unsigned short* __restrict__ WaT, unsigned short* __restrict__ wcp_c,
    unsigned short* __restrict__ wep_c, unsigned short* __restrict__ xc_c,
    unsigned short* __restrict__ xe_c) {
  __shared__ __align__(16) char sm[64 * 65 * 4];
  int b = blockIdx.x;
  int t = threadIdx.x;
  if (b >= 768) {
    int tb = b - 768;
    float(*ts)[65] = (float(*)[65])sm;
    int k0 = (tb >> 3) * 64, n0 = (tb & 7) * 64;
    int c = t & 63, r0 = t >> 6;
#pragma unroll
    for (int p = 0; p < 16; p++) {
      int r = r0 * 16 + p;
      ts[r][c] = Wa[(size_t)(k0 + r) * NHID + n0 + c];
    }
    __syncthreads();
    int n = t >> 2, q = t & 3;
    unsigned short tmp[16];
#pragma unroll
    for (int j = 0; j < 16; j++) tmp[j] = f2b(ts[q * 16 + j][n]);
    u16x8* dp = (u16x8*)(WaT + (size_t)(n0 + n) * (4 * NHID) + k0 + q * 16);
    dp[0] = *(u16x8*)tmp;
    dp[1] = *(u16x8*)(tmp + 8);
    return;
  }
  float(*red)[16][64] = (float(*)[16][64])sm;   // [4][16][64] = 16KB
  const int2* pair; const unsigned short* WT; const float* bias;
  unsigned short* out; unsigned short* xout; int base;
  if (b < NC / 16) { pair = c_pair; WT = WcT; bias = bc; out = wcp_c; xout = xc_c; base = b * 16; }
  else             { pair = e_pair; WT = WeT; bias = be; out = wep_c; xout = xe_c; base = (b - NC / 16) * 16; }
  int lane = t & 63, kh = t >> 6;     // kh = 4-way K-split
  int ln = lane & 15, kb = lane >> 4;
  const float* xr = x + (size_t)pair[base + ln].y * NHID + kh * 128;
  unsigned short* xw = xout + (size_t)(base + ln) * NHID + kh * 128;
  const unsigned short* wb = WT + kh * 128;
  f32x4 acc[4];
#pragma unroll
  for (int nt = 0; nt < 4; nt++) acc[nt] = (f32x4){0.f, 0.f, 0.f, 0.f};
#pragma unroll
  for (int kt = 0; kt < 4; kt++) {
    int k0 = kt * 32 + kb * 8;
    float4 p0 = *(const float4*)(xr + k0);
    float4 p1 = *(const float4*)(xr + k0 + 4);
    s16x8 a;
    a[0] = (short)f2b(p0.x); a[1] = (short)f2b(p0.y);
    a[2] = (short)f2b(p0.z); a[3] = (short)f2b(p0.w);
    a[4] = (short)f2b(p1.x); a[5] = (short)f2b(p1.y);
    a[6] = (short)f2b(p1.z); a[7] = (short)f2b(p1.w);
    *(u16x8*)(xw + k0) = (u16x8)a;   // export bf16 row (compacted order)
#pragma unroll
    for (int nt = 0; nt < 4; nt++) {
      s16x8 bf = *(const s16x8*)(wb + (size_t)(nt * 16 + ln) * NHID + k0);
      acc[nt] = __builtin_amdgcn_mfma_f32_16x16x32_bf16(a, bf, acc[nt], 0, 0, 0);
    }
  }
#pragma unroll
  for (int nt = 0; nt < 4; nt++)
#pragma unroll
    for (int r = 0; r < 4; r++)
      red[kh][kb * 4 + r][nt * 16 + ln] = acc[nt][r];
  __syncthreads();
  for (int i = t; i < 512; i += 256) {
    int row = i >> 5, cp = i & 31;
    int c0 = cp * 2;
    float v0 = red[0][row][c0] + red[1][row][c0] + red[2][row][c0] + red[3][row][c0] + bias[c0];
    float v1 = red[0][row][c0 + 1] + red[1][row][c0 + 1] + red[2][row][c0 + 1] + red[3][row][c0 + 1] + bias[c0 + 1];
    unsigned int pk = (unsigned)f2b(v0) | ((unsigned)f2b(v1) << 16);
    *(unsigned int*)(out + (size_t)(base + row) * PROJ + c0) = pk;
  }
}

// ---------------- k_attn: MFMA attention, fully-contiguous staging from compacted buffers ----------------
__global__ __launch_bounds__(512, 2) void k_attn(
    const unsigned short* __restrict__ xc_c, const unsigned short* __restrict__ xe_c,
    const unsigned short* __restrict__ wcp_c, const unsigned short* __restrict__ wep_c,
    const int* __restrict__ c_off, const int* __restrict__ c_cnt,
    const int* __restrict__ e_off, const int* __restrict__ e_cnt,
    unsigned short* __restrict__ mcb) {
  __shared__ __align__(16) char smem[SMEM_BYTES];
  unsigned short* P_s  = (unsigned short*)(smem);
  unsigned short* we_s = (unsigned short*)(smem + REGB_OFF);
  unsigned short* wc_s = (unsigned short*)(smem + WC_S_OFF);
  unsigned short* evT  = (unsigned short*)(smem + REGB_OFF);
  unsigned int*   evT32 = (unsigned int*)(smem + REGB_OFF);
  float*          cn_s = (float*)(smem + REGB_OFF);
  float*          pp   = (float*)(smem);          // reuses dead P_s region post-PV

  int g = blockIdx.x >> 2;
  int ds = blockIdx.x & 3;
  int dsbase = ds * DW;
  int t = threadIdx.x, lane = t & 63, w = t >> 6;
  int ln = lane & 15, kb = lane >> 4;

  int ne = min(e_cnt[g], NE_CAP);
  int eoff = e_off[g];
  int ccnt_full = c_cnt[g];
  int nloc = min(ccnt_full, NCMAX);
  int coff = c_off[g];
  if (nloc <= 0) {
    int q = t >> 7, d = t & 127;
    mcb[(size_t)g * 4 * NHID + q * NHID + dsbase + d] = 0;
    return;
  }
  int KT = (ne + 31) >> 5;
  int NT = KT * 2;

  // ---- phase 0: stage we_s + wc_s (CONTIGUOUS copies from compacted buffers) ----
  {
    int q = t & 7, er = t >> 3;
    for (int base_ = 0; base_ < NE_CAP; base_ += 64) {
      int e = base_ + er;
      u16x8 v = (u16x8){0, 0, 0, 0, 0, 0, 0, 0};
      if (e < ne) v = *(const u16x8*)(wep_c + (size_t)(eoff + e) * PROJ + q * 8);
      *(u16x8*)(we_s + e * WE_S_STRIDE + q * 8) = v;
    }
    for (int base_ = 0; base_ < NCMAX; base_ += 64) {
      int c = base_ + er;
      u16x8 v = (u16x8){0, 0, 0, 0, 0, 0, 0, 0};
      if (c < nloc) v = *(const u16x8*)(wcp_c + (size_t)(coff + c) * PROJ + q * 8);
      *(u16x8*)(wc_s + c * WE_S_STRIDE + q * 8) = v;
    }
  }
  __syncthreads();

  // ---- score phase: S = wc @ we^T via MFMA ----
  {
    f32x4 sa[16];
#pragma unroll
    for (int i = 0; i < 16; i++) sa[i] = (f32x4){0.f, 0.f, 0.f, 0.f};
    const unsigned short* arow = wc_s + ((w << 4) + ln) * WE_S_STRIDE;
#pragma unroll
    for (int ks = 0; ks < 2; ks++) {
      s16x8 af = *(const s16x8*)(arow + ks * 32 + kb * 8);
#pragma unroll
      for (int nt = 0; nt < 16; nt++) {
        if (nt < NT) {
          s16x8 bf = *(const s16x8*)(we_s + (nt * 16 + ln) * WE_S_STRIDE + ks * 32 + kb * 8);
          sa[nt] = __builtin_amdgcn_mfma_f32_16x16x32_bf16(af, bf, sa[nt], 0, 0, 0);
        }
      }
    }
#pragma unroll
    for (int r = 0; r < 4; r++) {
      int claim = (w << 4) + (kb << 2) + r;
      float mx = -1e30f;
#pragma unroll
      for (int nt = 0; nt < 16; nt++) {
        if (nt < NT) {
          float v = sa[nt][r];
          v = (nt * 16 + ln < ne) ? v : -1e30f;
          sa[nt][r] = v;
          mx = fmaxf(mx, v);
        }
      }
      mx = fmaxf(mx, __shfl_xor(mx, 1));
      mx = fmaxf(mx, __shfl_xor(mx, 2));
      mx = fmaxf(mx, __shfl_xor(mx, 4));
      mx = fmaxf(mx, __shfl_xor(mx, 8));
      float sum = 0.f;
#pragma unroll
      for (int nt = 0; nt < 16; nt++) {
        if (nt < NT) {
          float p = __expf(sa[nt][r] - mx);
          sa[nt][r] = p;
          sum += p;
        }
      }
      sum += __shfl_xor(sum, 1);
      sum += __shfl_xor(sum, 2);
      sum += __shfl_xor(sum, 4);
      sum += __shfl_xor(sum, 8);
      float inv = 1.f / sum;
#pragma unroll
      for (int nt = 0; nt < 16; nt++) {
        if (nt < NT)
          P_s[claim * P_S_STRIDE + nt * 16 + ln] = f2b(sa[nt][r] * inv);
      }
    }
  }
  __syncthreads();   // we_s dead; P_s ready

  // ---- evT staging: contiguous bf16 slab, (ep8 x j8) lane map ----
  // global: 128B contiguous per (row, j8-group); LDS: 8-way write conflict max.
#pragma unroll
  for (int it = 0; it < 4; it++) {
    int idx2 = it * 512 + t;              // [ep_hi:4][j8:4][ep_lo:3]
    int ep = ((idx2 >> 7) << 3) | (idx2 & 7);
    int j8 = (idx2 >> 3) & 15;
    int d0 = j8 * 8;
    int e0 = ep * 2;
    u16x8 va = (u16x8){0, 0, 0, 0, 0, 0, 0, 0};
    u16x8 vb = (u16x8){0, 0, 0, 0, 0, 0, 0, 0};
    if (e0 < ne)     va = *(const u16x8*)(xe_c + (size_t)(eoff + e0) * NHID + dsbase + d0);
    if (e0 + 1 < ne) vb = *(const u16x8*)(xe_c + (size_t)(eoff + e0 + 1) * NHID + dsbase + d0);
#pragma unroll
    for (int j = 0; j < 8; j++)
      evT32[(d0 + j) * (P_S_STRIDE / 2) + ep] =
          (unsigned)(unsigned short)va[j] | ((unsigned)(unsigned short)vb[j] << 16);
  }
  __syncthreads();

  // ---- T14: issue claim-row loads (bf16, contiguous) for pooled phase ----
  int dq4 = (t & 31) * 4;
  int mg = t >> 5;     // 0..15
  ushort4 cl_u[8];
#pragma unroll
  for (int mi = 0; mi < 8; mi++) {
    int m = mg + mi * 16;
    cl_u[mi] = make_ushort4(0, 0, 0, 0);
    if (m < nloc)
      cl_u[mi] = *(const ushort4*)(xc_c + (size_t)(coff + m) * NHID + dsbase + dq4);
  }

  // ---- PV phase ----
  int mw = w >> 1, nw = w & 1;
  int m0 = mw * 32, n0 = nw * 64;
  f32x4 pc[8];
#pragma unroll
  for (int i = 0; i < 8; i++) pc[i] = (f32x4){0.f, 0.f, 0.f, 0.f};
  {
    const unsigned short* prow0 = P_s + (m0 + ln) * P_S_STRIDE + kb * 8;
    const unsigned short* prow1 = prow0 + 16 * P_S_STRIDE;
#pragma unroll
    for (int kt = 0; kt < 8; kt++) {
      if (kt < KT) {
        int k0 = kt * 32;
        s16x8 a0 = *(const s16x8*)(prow0 + k0);
        s16x8 a1 = *(const s16x8*)(prow1 + k0);
#pragma unroll
        for (int nt = 0; nt < 4; nt++) {
          s16x8 bf = *(const s16x8*)(evT + (n0 + nt * 16 + ln) * P_S_STRIDE + k0 + kb * 8);
          pc[nt]     = __builtin_amdgcn_mfma_f32_16x16x32_bf16(a0, bf, pc[nt], 0, 0, 0);
          pc[4 + nt] = __builtin_amdgcn_mfma_f32_16x16x32_bf16(a1, bf, pc[4 + nt], 0, 0, 0);
        }
      }
    }
  }
  __syncthreads();   // P_s dead from here; pp may reuse its region

  // ---- dump cn to LDS ----
#pragma unroll
  for (int mi = 0; mi < 2; mi++) {
#pragma unroll
    for (int nt = 0; nt < 4; nt++) {
      f32x4 v = pc[mi * 4 + nt];
#pragma unroll
      for (int r = 0; r < 4; r++)
        cn_s[(m0 + mi * 16 + (kb << 2) + r) * CN_S_STRIDE + n0 + nt * 16 + ln] = v[r];
    }
  }
  __syncthreads();

  // ---- pooled sums: staged bf16 claim regs + cn_s, partials into pp ----
  {
    float4 scl = make_float4(0.f, 0.f, 0.f, 0.f);
    float4 scn = make_float4(0.f, 0.f, 0.f, 0.f);
    float4 spr = make_float4(0.f, 0.f, 0.f, 0.f);
#pragma unroll
    for (int mi = 0; mi < 8; mi++) {
      int m = mg + mi * 16;
      if (m < nloc) {
        float clx = b2f(cl_u[mi].x), cly = b2f(cl_u[mi].y);
        float clz = b2f(cl_u[mi].z), clw = b2f(cl_u[mi].w);
        float4 cn = *(const float4*)(cn_s + m * CN_S_STRIDE + dq4);
        scl.x += clx; scl.y += cly; scl.z += clz; scl.w += clw;
        scn.x += cn.x; scn.y += cn.y; scn.z += cn.z; scn.w += cn.w;
        spr.x += clx * cn.x; spr.y += cly * cn.y;
        spr.z += clz * cn.z; spr.w += clw * cn.w;
      }
    }
    *(float4*)(pp + mg * 128 + dq4) = scl;
    *(float4*)(pp + 2048 + mg * 128 + dq4) = scn;
    *(float4*)(pp + 4096 + mg * 128 + dq4) = spr;
  }
  __syncthreads();

  // ---- fused mean-concat epilogue ----
  {
    int q = t >> 7, d = t & 127;
    float inv = 1.f / (float)max(ccnt_full, 1);
    float v = 0.f;
    if (q == 0) {
#pragma unroll
      for (int mg2 = 0; mg2 < 16; mg2++) v += pp[mg2 * 128 + d];
    } else if (q == 1) {
#pragma unroll
      for (int mg2 = 0; mg2 < 16; mg2++) v += pp[2048 + mg2 * 128 + d];
    } else if (q == 2) {
#pragma unroll
      for (int mg2 = 0; mg2 < 16; mg2++) v += pp[mg2 * 128 + d] - pp[2048 + mg2 * 128 + d];
    } else {
#pragma unroll
      for (int mg2 = 0; mg2 < 16; mg2++) v += pp[4096 + mg2 * 128 + d];
    }
    mcb[(size_t)g * 4 * NHID + q * NHID + dsbase + d] = f2b(v * inv);
  }
}

// ---------------- k_out: 32 blocks, 16-col n-tiles, 2-way K-split ----------------
__global__ __launch_bounds__(512) void k_out(
    const unsigned short* __restrict__ mc, const unsigned short* __restrict__ WaT,
    const float* __restrict__ ba, float* __restrict__ out) {
  __shared__ float red[2][64][16];   // 8KB
  int n0 = blockIdx.x * 16;
  int t = threadIdx.x, lane = t & 63, wv = t >> 6;
  int mh = wv & 3, kh = wv >> 2;
  int ln = lane & 15, kb = lane >> 4;
  f32x4 acc = (f32x4){0.f, 0.f, 0.f, 0.f};
  const unsigned short* arow = mc + (size_t)(mh * 16 + ln) * (4 * NHID) + kh * 1024;
  const unsigned short* wcol = WaT + (size_t)(n0 + ln) * (4 * NHID) + kh * 1024;
#pragma unroll 4
  for (int kt = 0; kt < 32; kt++) {
    int k0 = kt * 32 + kb * 8;
    s16x8 af = *(const s16x8*)(arow + k0);
    s16x8 bf = *(const s16x8*)(wcol + k0);
    acc = __builtin_amdgcn_mfma_f32_16x16x32_bf16(af, bf, acc, 0, 0, 0);
  }
#pragma unroll
  for (int r = 0; r < 4; r++)
    red[kh][mh * 16 + kb * 4 + r][ln] = acc[r];
  __syncthreads();
  for (int i = t; i < 1024; i += 512) {
    int row = i >> 4, col = i & 15;
    out[(size_t)row * NHID + n0 + col] = red[0][row][col] + red[1][row][col] + ba[n0 + col];
  }
}

extern "C" void kernel_launch(void* const* d_in, const int* in_sizes, int n_in,
                              void* d_out, int out_size, void* d_ws, size_t ws_size,
                              hipStream_t stream) {
  const float* x = (const float*)d_in[0];
  const int* batch = (const int*)d_in[1];
  const int* cidx = (const int*)d_in[2];
  const int* eidx = (const int*)d_in[3];
  const float* Wc = (const float*)d_in[4];
  const float* bc = (const float*)d_in[5];
  const float* We = (const float*)d_in[6];
  const float* be = (const float*)d_in[7];
  const float* Wa = (const float*)d_in[8];
  const float* ba = (const float*)d_in[9];
  float* out = (float*)d_out;

  char* w = (char*)d_ws;
  int* c_off = (int*)w;    w += NG * 4;
  int* c_cnt = (int*)w;    w += NG * 4;
  int* e_off = (int*)w;    w += NG * 4;
  int* e_cnt = (int*)w;    w += NG * 4;
  int2* c_pair = (int2*)w; w += (size_t)NC * 8;
  int2* e_pair = (int2*)w; w += (size_t)NEV * 8;
  unsigned short* wcp_c = (unsigned short*)w; w += (size_t)NC * PROJ * 2;
  unsigned short* wep_c = (unsigned short*)w; w += (size_t)NEV * PROJ * 2;
  unsigned short* WcT = (unsigned short*)w;   w += (size_t)PROJ * NHID * 2;
  unsigned short* WeT = (unsigned short*)w;   w += (size_t)PROJ * NHID * 2;
  unsigned short* WaT = (unsigned short*)w;   w += (size_t)NHID * 4 * NHID * 2;
  unsigned short* mcb = (unsigned short*)w;   w += (size_t)NG * 4 * NHID * 2;
  unsigned short* xc_c = (unsigned short*)w;  w += (size_t)NC * NHID * 2;
  unsigned short* xe_c = (unsigned short*)w;  w += (size_t)NEV * NHID * 2;

  k_front<<<144, 256, 0, stream>>>(Wc, We, WcT, WeT, batch, cidx, eidx,
                                   c_off, c_cnt, c_pair, e_off, e_cnt, e_pair);
  k_proj<<<768 + 256, 256, 0, stream>>>(x, c_pair, e_pair, WcT, WeT, bc, be, Wa, WaT,
                                        wcp_c, wep_c, xc_c, xe_c);
  k_attn<<<NG * DSLICES, 512, 0, stream>>>(xc_c, xe_c, wcp_c, wep_c,
                                           c_off, c_cnt, e_off, e_cnt, mcb);
  k_out<<<32, 512, 0, stream>>>(mcb, WaT, ba, out);
}